// Round 5
// baseline (9866.235 us; speedup 1.0000x reference)
//
#include <hip/hip_runtime.h>
#include <cstdint>
#include <cstddef>

#define T_OBS_C 64
#define T_UNOBS_C 32
#define BATCH_C 4096
#define HID_C 256

typedef short v8s __attribute__((ext_vector_type(8)));
typedef float v4f __attribute__((ext_vector_type(4)));
typedef unsigned short u16x8 __attribute__((ext_vector_type(8)));
typedef unsigned short u16x4 __attribute__((ext_vector_type(4)));

__device__ __forceinline__ float bf2f(unsigned short u) {
  union { unsigned int i; float f; } v; v.i = ((unsigned int)u) << 16; return v.f;
}
__device__ __forceinline__ unsigned short f2bf(float f) {
  union { float f; unsigned int i; } v; v.f = f;
  unsigned int r = (v.i + 0x7FFFu + ((v.i >> 16) & 1u)) >> 16;
  return (unsigned short)r;
}

// ---------------------------------------------------------------------------
// prep:
//   Wc = wi @ stem_w2  (fp32, so gx_t = stem1_t @ Wc.T + bc_obs)  -> hi/lo bf16
//   wi, wh -> hi/lo bf16 splits
//   bc_obs[n] = sum_j wi[n][j]*b2[j] + bi[n]   (fp32)
// ---------------------------------------------------------------------------
__global__ void prep_kernel(const float* __restrict__ wi,
                            const float* __restrict__ w2,
                            const float* __restrict__ b2,
                            const float* __restrict__ bi,
                            unsigned short* __restrict__ wi_hi,
                            unsigned short* __restrict__ wi_lo,
                            const float* __restrict__ wh,
                            unsigned short* __restrict__ wh_hi,
                            unsigned short* __restrict__ wh_lo,
                            unsigned short* __restrict__ wc_hi,
                            unsigned short* __restrict__ wc_lo,
                            float* __restrict__ bc_obs) {
  const int n = blockIdx.x;     // 0..767
  const int k = threadIdx.x;    // 0..255
  const int idx = n * 256 + k;

  float wv = wi[idx];
  unsigned short h1 = f2bf(wv);
  wi_hi[idx] = h1; wi_lo[idx] = f2bf(wv - bf2f(h1));

  float hv = wh[idx];
  unsigned short h2 = f2bf(hv);
  wh_hi[idx] = h2; wh_lo[idx] = f2bf(hv - bf2f(h2));

  float acc = 0.f;
  for (int j = 0; j < 256; ++j)
    acc += wi[n * 256 + j] * w2[j * 256 + k];
  unsigned short h3 = f2bf(acc);
  wc_hi[idx] = h3; wc_lo[idx] = f2bf(acc - bf2f(h3));

  if (k == 0) {
    float b = 0.f;
    for (int j = 0; j < 256; ++j) b += wi[n * 256 + j] * b2[j];
    bc_obs[n] = b + bi[n];
  }
}

struct BFrag6 { v8s h[3]; v8s l[3]; };
struct AFrag  { v8s hi; v8s lo; };

// ---------------------------------------------------------------------------
// Persistent RNN kernel: 256 blocks x 512 threads (1 block/CU). Block b owns
// batch rows [b*16, b*16+16) and ALL 768 gate columns -> fully independent
// blocks, no grid sync. h lives in LDS (hi/lo bf16). Weights stream from
// L2/L3 each step with a manual 2-deep prefetch pipeline. head is fused.
// __launch_bounds__(512, 2): 2 waves/EU min = 1 block/CU -> full 256-VGPR
// budget per wave, no spill (round-2 run spilled at the default 128 budget).
// ---------------------------------------------------------------------------
__global__ __launch_bounds__(512, 2)
void rnn_persistent(const float* __restrict__ x_obs,
                    const float* __restrict__ t_obs,
                    const float* __restrict__ w1,
                    const float* __restrict__ b1,
                    const unsigned short* __restrict__ wi_hi,
                    const unsigned short* __restrict__ wi_lo,
                    const unsigned short* __restrict__ wh_hi,
                    const unsigned short* __restrict__ wh_lo,
                    const unsigned short* __restrict__ wc_hi,
                    const unsigned short* __restrict__ wc_lo,
                    const float* __restrict__ bc_obs,
                    const float* __restrict__ bi,
                    const float* __restrict__ bh,
                    const float* __restrict__ head_w,
                    const float* __restrict__ head_b,
                    float* __restrict__ out_x,
                    float* __restrict__ out_z) {
  // 16 rows x 256 cols, hi+lo, XOR-swizzled per 8-elem chunk: 4 x 8KB = 32KB
  __shared__ __align__(16) unsigned short lds_h_hi[4096];
  __shared__ __align__(16) unsigned short lds_h_lo[4096];
  __shared__ __align__(16) unsigned short lds_x_hi[4096];
  __shared__ __align__(16) unsigned short lds_x_lo[4096];

  const int tid  = threadIdx.x;
  const int m0   = blockIdx.x << 4;      // 16 batch rows per block
  const int wave = tid >> 6;             // 0..7
  const int lane = tid & 63;
  const int quad = lane >> 4;
  const int l16  = lane & 15;
  const int jw   = wave << 5;            // this wave's 32 gate-cols

  // h0 = 0
  for (int i = tid; i < 4096; i += 512) { lds_h_hi[i] = 0; lds_h_lo[i] = 0; }

  // per-thread epilogue biases (jcol fixed for the whole kernel)
  float xb_o[2][3], xb_a[2][3], hb_[2][3];
  #pragma unroll
  for (int nf = 0; nf < 2; ++nf) {
    const int jc = jw + nf * 16 + l16;
    #pragma unroll
    for (int g = 0; g < 3; ++g) {
      xb_o[nf][g] = bc_obs[g * 256 + jc];
      xb_a[nf][g] = bi[g * 256 + jc];
      hb_[nf][g]  = bh[g * 256 + jc];
    }
  }

  // fused-head thread mapping: (row, d, k-slice)
  const int xr_row = tid >> 5;           // 0..15
  const int xr_d   = (tid >> 3) & 3;     // 0..3
  const int xr_ks  = tid & 7;            // 0..7  (32 k each)
  const float hb_d = head_b[xr_d];

  __syncthreads();

  // ---- one GRU step: pipelined GEMM (x-path, h-path) + gate epilogue ----
  // 32 micro-iterations: i2 -> s = i2>>4 (path), kc = (i2>>1)&7, nf = i2&1.
  // B-fragments prefetched 2 iterations ahead (3 live sets of 6 v8s);
  // A-fragments (LDS) prefetched 1 kc ahead. All indices fold at compile time
  // under the full unroll (no runtime-indexed register arrays).
  auto do_step = [&](const unsigned short* a0h, const unsigned short* a0l,
                     const unsigned short* bx_h, const unsigned short* bx_l,
                     int obsflag) {
    v4f acc[2][6];
    #pragma unroll
    for (int nf = 0; nf < 2; ++nf)
      #pragma unroll
      for (int q = 0; q < 6; ++q)
        acc[nf][q] = (v4f){0.f, 0.f, 0.f, 0.f};

    auto ldB = [&](int i) -> BFrag6 {
      BFrag6 f;
      const int s = i >> 4, kc = (i >> 1) & 7, nf = i & 1;
      const unsigned short* bhp = s ? wh_hi : bx_h;
      const unsigned short* blp = s ? wh_lo : bx_l;
      #pragma unroll
      for (int g = 0; g < 3; ++g) {
        const int bo = ((g * 256 + jw + nf * 16 + l16) << 8) + kc * 32 + quad * 8;
        f.h[g] = *(const v8s*)(bhp + bo);
        f.l[g] = *(const v8s*)(blp + bo);
      }
      return f;
    };
    auto ldA = [&](int iq) -> AFrag {   // iq = (s*8 + kc), 0..15
      AFrag a;
      const int s = iq >> 3, kc = iq & 7;
      const unsigned short* ahp = s ? lds_h_hi : a0h;
      const unsigned short* alp = s ? lds_h_lo : a0l;
      const int chunk = (kc * 4 + quad) ^ (l16 & 7);
      const int aoff = (l16 << 8) + (chunk << 3);
      a.hi = *(const v8s*)(ahp + aoff);
      a.lo = *(const v8s*)(alp + aoff);
      return a;
    };

    BFrag6 b0 = ldB(0);
    BFrag6 b1 = ldB(1);
    AFrag  ac = ldA(0);
    AFrag  an = ac;

    #pragma unroll
    for (int i2 = 0; i2 < 32; ++i2) {
      const int s  = i2 >> 4;
      const int iq = i2 >> 1;
      const int nf = i2 & 1;
      BFrag6 b2 = b1;
      if (i2 + 2 < 32) b2 = ldB(i2 + 2);
      if (nf == 0 && iq + 1 < 16) an = ldA(iq + 1);
      #pragma unroll
      for (int g = 0; g < 3; ++g) {
        acc[nf][s * 3 + g] = __builtin_amdgcn_mfma_f32_16x16x32_bf16(
            ac.hi, b0.h[g], acc[nf][s * 3 + g], 0, 0, 0);
        acc[nf][s * 3 + g] = __builtin_amdgcn_mfma_f32_16x16x32_bf16(
            ac.lo, b0.h[g], acc[nf][s * 3 + g], 0, 0, 0);
        acc[nf][s * 3 + g] = __builtin_amdgcn_mfma_f32_16x16x32_bf16(
            ac.hi, b0.l[g], acc[nf][s * 3 + g], 0, 0, 0);
      }
      b0 = b1; b1 = b2;
      if (nf == 1) ac = an;
    }

    __syncthreads();  // all MFMA LDS reads done before h is overwritten

    #pragma unroll
    for (int nf = 0; nf < 2; ++nf) {
      const int jcol = jw + nf * 16 + l16;
      #pragma unroll
      for (int rg = 0; rg < 4; ++rg) {
        const int rl = quad * 4 + rg;   // local row 0..15
        const float xbr = obsflag ? xb_o[nf][0] : xb_a[nf][0];
        const float xbz = obsflag ? xb_o[nf][1] : xb_a[nf][1];
        const float xbn = obsflag ? xb_o[nf][2] : xb_a[nf][2];
        float gr = acc[nf][0][rg] + xbr + acc[nf][3][rg] + hb_[nf][0];
        float gz = acc[nf][1][rg] + xbz + acc[nf][4][rg] + hb_[nf][1];
        float nx = acc[nf][2][rg] + xbn;
        float nh = acc[nf][5][rg] + hb_[nf][2];
        float r = 1.f / (1.f + expf(-gr));
        float u = 1.f / (1.f + expf(-gz));
        float n = tanhf(nx + r * nh);
        const int hp = (rl << 8) + ((((jcol >> 3) ^ (rl & 7))) << 3) + (jcol & 7);
        float hold = bf2f(lds_h_hi[hp]) + bf2f(lds_h_lo[hp]);
        float hnew = (1.f - u) * n + u * hold;
        unsigned short hi = f2bf(hnew);
        lds_h_hi[hp] = hi;
        lds_h_lo[hp] = f2bf(hnew - bf2f(hi));
      }
    }
  };

  // ---- fused z + head output: out_z[zi] and out_x[zi] from LDS h ----
  // z-store: lane-contiguous float4 (two coalesced passes of 8KB).
  auto emit = [&](int zi) {
    __syncthreads();  // epilogue h writes visible
    #pragma unroll
    for (int p = 0; p < 2; ++p) {
      const int idx  = p * 512 + tid;     // 4-float chunk index, 0..1023
      const int row  = idx >> 6;          // 0..15
      const int col4 = idx & 63;          // 4-col group
      const int phys = (row << 8) + ((((col4 >> 1) ^ (row & 7))) << 3) + ((col4 & 1) << 2);
      const u16x4 vh = *(const u16x4*)(lds_h_hi + phys);
      const u16x4 vl = *(const u16x4*)(lds_h_lo + phys);
      float4 o;
      o.x = bf2f(vh[0]) + bf2f(vl[0]);
      o.y = bf2f(vh[1]) + bf2f(vl[1]);
      o.z = bf2f(vh[2]) + bf2f(vl[2]);
      o.w = bf2f(vh[3]) + bf2f(vl[3]);
      *(float4*)(out_z + ((size_t)zi << 20) + ((size_t)m0 << 8) + (size_t)idx * 4) = o;
    }
    // head: x_hat = h @ head_w.T + head_b
    float accx = 0.f;
    #pragma unroll
    for (int c = 0; c < 4; ++c) {
      const int k8 = xr_ks * 4 + c;
      const int hp = (xr_row << 8) + ((k8 ^ (xr_row & 7)) << 3);
      const u16x8 vh = *(const u16x8*)(lds_h_hi + hp);
      const u16x8 vl = *(const u16x8*)(lds_h_lo + hp);
      float f[8];
      #pragma unroll
      for (int j = 0; j < 8; ++j) f[j] = bf2f(vh[j]) + bf2f(vl[j]);
      const float* wd = head_w + xr_d * 256 + k8 * 8;
      const float4 w0 = *(const float4*)(wd);
      const float4 w1v = *(const float4*)(wd + 4);
      accx += f[0] * w0.x + f[1] * w0.y + f[2] * w0.z + f[3] * w0.w;
      accx += f[4] * w1v.x + f[5] * w1v.y + f[6] * w1v.z + f[7] * w1v.w;
    }
    accx += __shfl_xor(accx, 1);
    accx += __shfl_xor(accx, 2);
    accx += __shfl_xor(accx, 4);
    if (xr_ks == 0)
      out_x[(((size_t)zi << 12) + m0 + xr_row) * 4 + xr_d] = accx + hb_d;
  };

  // ================= observed phase: 64 steps =================
  #pragma unroll 1
  for (int t = 0; t < T_OBS_C; ++t) {
    // stem1 = leaky_relu(xt @ w1.T + b1), exact fp32, into lds_x (hi/lo)
    {
      const int row = tid >> 5;          // 0..15
      const int cg  = tid & 31;          // 8-col group
      const size_t xo = (size_t)t * BATCH_C + m0 + row;
      const float4 xv = *(const float4*)(x_obs + xo * 4);
      float td = 0.f;
      if (t > 0) td = t_obs[xo] - t_obs[xo - BATCH_C];
      const float* wr = w1 + cg * 40;    // 8 rows x 5, contiguous
      u16x8 hi8, lo8;
      #pragma unroll
      for (int j = 0; j < 8; ++j) {
        float pre = xv.x * wr[j * 5 + 0] + xv.y * wr[j * 5 + 1] +
                    xv.z * wr[j * 5 + 2] + xv.w * wr[j * 5 + 3] +
                    td * wr[j * 5 + 4] + b1[cg * 8 + j];
        float a = (pre > 0.f) ? pre : 0.01f * pre;   // leaky_relu slope 0.01
        unsigned short h = f2bf(a);
        hi8[j] = h;
        lo8[j] = f2bf(a - bf2f(h));
      }
      const int phys = (row << 8) + ((cg ^ (row & 7)) << 3);
      *(u16x8*)(lds_x_hi + phys) = hi8;
      *(u16x8*)(lds_x_lo + phys) = lo8;
    }
    __syncthreads();
    do_step(lds_x_hi, lds_x_lo, wc_hi, wc_lo, 1);
  }
  emit(0);  // z_last

  // ================= autoregressive phase: 31 steps =================
  #pragma unroll 1
  for (int i = 1; i < T_UNOBS_C; ++i) {
    __syncthreads();  // prior h writes / emit reads complete
    do_step(lds_h_hi, lds_h_lo, wi_hi, wi_lo, 0);
    emit(i);
  }
}

// ---------------------------------------------------------------------------
extern "C" void kernel_launch(void* const* d_in, const int* in_sizes, int n_in,
                              void* d_out, int out_size, void* d_ws, size_t ws_size,
                              hipStream_t stream) {
  const float* x_obs = (const float*)d_in[0];
  const float* t_obs = (const float*)d_in[1];
  // d_in[2] = t_unobs: only its length (32) matters
  const float* w1 = (const float*)d_in[3];
  const float* b1 = (const float*)d_in[4];
  const float* w2 = (const float*)d_in[5];
  const float* b2 = (const float*)d_in[6];
  const float* wi = (const float*)d_in[7];
  const float* wh = (const float*)d_in[8];
  const float* bi = (const float*)d_in[9];
  const float* bh = (const float*)d_in[10];
  const float* hw = (const float*)d_in[11];
  const float* hb = (const float*)d_in[12];

  float* out_x = (float*)d_out;                                  // [32,4096,4]
  float* out_z = out_x + (size_t)T_UNOBS_C * BATCH_C * 4;        // [32,4096,256]

  // workspace: weight splits only (~2.4 MB)
  unsigned short* p = (unsigned short*)d_ws;
  unsigned short* wi_hi = p; p += 768 * 256;
  unsigned short* wi_lo = p; p += 768 * 256;
  unsigned short* wh_hi = p; p += 768 * 256;
  unsigned short* wh_lo = p; p += 768 * 256;
  unsigned short* wc_hi = p; p += 768 * 256;
  unsigned short* wc_lo = p; p += 768 * 256;
  float* bc_obs = (float*)p;

  prep_kernel<<<768, 256, 0, stream>>>(wi, w2, b2, bi,
                                       wi_hi, wi_lo, wh, wh_hi, wh_lo,
                                       wc_hi, wc_lo, bc_obs);

  rnn_persistent<<<256, 512, 0, stream>>>(x_obs, t_obs, w1, b1,
                                          wi_hi, wi_lo, wh_hi, wh_lo,
                                          wc_hi, wc_lo, bc_obs, bi, bh,
                                          hw, hb, out_x, out_z);
}

// Round 6
// 3287.655 us; speedup vs baseline: 3.0010x; 3.0010x over previous
//
#include <hip/hip_runtime.h>
#include <cstdint>
#include <cstddef>

#define T_OBS_C 64
#define T_UNOBS_C 32
#define BATCH_C 4096
#define HID_C 256

typedef short v8s __attribute__((ext_vector_type(8)));
typedef float v4f __attribute__((ext_vector_type(4)));
typedef unsigned short u16x8 __attribute__((ext_vector_type(8)));

__device__ __forceinline__ float bf2f(unsigned short u) {
  union { unsigned int i; float f; } v; v.i = ((unsigned int)u) << 16; return v.f;
}
__device__ __forceinline__ unsigned short f2bf(float f) {
  union { float f; unsigned int i; } v; v.f = f;
  unsigned int r = (v.i + 0x7FFFu + ((v.i >> 16) & 1u)) >> 16;
  return (unsigned short)r;
}

// ---------------------------------------------------------------------------
// prep (unchanged, verified):
//   Wc = wi @ stem_w2  -> hi/lo bf16 ; wi, wh -> hi/lo bf16
//   bc_obs[n] = sum_j wi[n][j]*b2[j] + bi[n]
// ---------------------------------------------------------------------------
__global__ void prep_kernel(const float* __restrict__ wi,
                            const float* __restrict__ w2,
                            const float* __restrict__ b2,
                            const float* __restrict__ bi,
                            unsigned short* __restrict__ wi_hi,
                            unsigned short* __restrict__ wi_lo,
                            const float* __restrict__ wh,
                            unsigned short* __restrict__ wh_hi,
                            unsigned short* __restrict__ wh_lo,
                            unsigned short* __restrict__ wc_hi,
                            unsigned short* __restrict__ wc_lo,
                            float* __restrict__ bc_obs) {
  const int n = blockIdx.x;     // 0..767
  const int k = threadIdx.x;    // 0..255
  const int idx = n * 256 + k;

  float wv = wi[idx];
  unsigned short h1 = f2bf(wv);
  wi_hi[idx] = h1; wi_lo[idx] = f2bf(wv - bf2f(h1));

  float hv = wh[idx];
  unsigned short h2 = f2bf(hv);
  wh_hi[idx] = h2; wh_lo[idx] = f2bf(hv - bf2f(h2));

  float acc = 0.f;
  for (int j = 0; j < 256; ++j)
    acc += wi[n * 256 + j] * w2[j * 256 + k];
  unsigned short h3 = f2bf(acc);
  wc_hi[idx] = h3; wc_lo[idx] = f2bf(acc - bf2f(h3));

  if (k == 0) {
    float b = 0.f;
    for (int j = 0; j < 256; ++j) b += wi[n * 256 + j] * b2[j];
    bc_obs[n] = b + bi[n];
  }
}

// ---------------------------------------------------------------------------
// Weight-stationary persistent RNN. 256 blocks = 16 row-groups (256 rows) x
// 16 col-groups (16 h-cols = 48 gate-rows). Block keeps its weight slice
// (wc,wi,wh x 48x256 hi/lo = 144KB) in LDS forever -> zero weight streaming.
// Per step: read A (stem or h) rows from global (L2-local), MFMA, epilogue
// writes h slice; 16-block row-group barrier (agent-scope atomics).
// Cooperative launch guarantees co-residency (1 block/CU via 144KB LDS).
// bid->(rg,cg) mapping puts all 16 blocks of an rg on one XCD (perf only).
// ---------------------------------------------------------------------------
__global__ __launch_bounds__(512, 2)
void rnn_xcd(const float* __restrict__ x_obs,
             const float* __restrict__ t_obs,
             const float* __restrict__ w1,
             const float* __restrict__ b1,
             const unsigned short* __restrict__ wc_hi, const unsigned short* __restrict__ wc_lo,
             const unsigned short* __restrict__ wi_hi, const unsigned short* __restrict__ wi_lo,
             const unsigned short* __restrict__ wh_hi, const unsigned short* __restrict__ wh_lo,
             const float* __restrict__ bc_obs,
             const float* __restrict__ bi,
             const float* __restrict__ bh,
             const float* __restrict__ head_w,
             const float* __restrict__ head_b,
             unsigned short* h_hi0, unsigned short* h_lo0,
             unsigned short* h_hi1, unsigned short* h_lo1,
             unsigned short* st_hi0, unsigned short* st_lo0,
             unsigned short* st_hi1, unsigned short* st_lo1,
             unsigned int* cnt,
             float* out_x,
             float* out_z) {
  // [ (mat*3+g)*2+hl ][16 rows][32 c16-chunks swizzled] = 18*4096 ushorts = 144KB
  __shared__ unsigned short wlds[73728];

  const int tid = threadIdx.x;
  const int bid = blockIdx.x;
  const int jj  = bid & 15;
  const int cg  = bid >> 4;
  const int rg  = ((jj & 7) << 1) | (jj >> 3);   // same-rg blocks share XCD (perf)
  const int m0  = rg << 8;                       // 256 rows per row-group
  const int c0  = cg << 4;                       // 16 h-cols per col-group

  // ---- one-time: load weight slices into LDS (XOR-swizzled rows) ----
  {
    const unsigned short* srcs[6] = {wc_hi, wc_lo, wi_hi, wi_lo, wh_hi, wh_lo};
    for (int id = tid; id < 9216; id += 512) {
      const int sub = id >> 9;                 // 0..17 == (mat*3+g)*2+hl
      const int mat = sub / 6;
      const int g   = (sub >> 1) % 3;
      const int hl  = sub & 1;
      const int within = id & 511;
      const int row = within >> 5;             // 0..15
      const int c16 = within & 31;             // 16B chunk within row
      const unsigned short* s = srcs[mat * 2 + hl] +
          (((size_t)(g * 256 + c0 + row)) << 8) + (c16 << 3);
      u16x8 v = *(const u16x8*)s;
      *(u16x8*)(wlds + (sub << 12) + (row << 8) + ((c16 ^ row) << 3)) = v;
    }
  }

  const int wave = tid >> 6;      // 0..7, owns m-tiles {2w, 2w+1}
  const int lane = tid & 63;
  const int quad = lane >> 4;
  const int l16  = lane & 15;
  const int jc   = c0 + l16;      // this thread's h-col

  float xb_o[3], xb_a[3], hb_[3], hwv[4];
  #pragma unroll
  for (int g = 0; g < 3; ++g) {
    xb_o[g] = bc_obs[g * 256 + jc];
    xb_a[g] = bi[g * 256 + jc];
    hb_[g]  = bh[g * 256 + jc];
  }
  #pragma unroll
  for (int d = 0; d < 4; ++d) hwv[d] = head_w[d * 256 + jc];

  const size_t rowA0 = (size_t)(m0 + (wave * 2 + 0) * 16 + l16) << 8;
  const size_t rowA1 = (size_t)(m0 + (wave * 2 + 1) * 16 + l16) << 8;

  // stem slice for time tt: this block's 256 rows x its 16 cols (exact fp32)
  auto stem_slice = [&](int tt, unsigned short* dh, unsigned short* dl) {
    const int row  = tid >> 1;        // 0..255
    const int half = tid & 1;
    const size_t grow = (size_t)(m0 + row);
    const size_t xo = (size_t)tt * BATCH_C + grow;
    const float4 xv = *(const float4*)(x_obs + xo * 4);
    float td = 0.f;
    if (tt > 0) td = t_obs[xo] - t_obs[xo - BATCH_C];
    const int j0 = c0 + half * 8;
    u16x8 hi8, lo8;
    #pragma unroll
    for (int j = 0; j < 8; ++j) {
      const int jg = j0 + j;
      const float* wr = w1 + jg * 5;
      float pre = xv.x * wr[0] + xv.y * wr[1] + xv.z * wr[2] +
                  xv.w * wr[3] + td * wr[4] + b1[jg];
      float a = (pre > 0.f) ? pre : 0.01f * pre;   // leaky_relu 0.01
      unsigned short h = f2bf(a);
      hi8[j] = h; lo8[j] = f2bf(a - bf2f(h));
    }
    *(u16x8*)(dh + (grow << 8) + j0) = hi8;
    *(u16x8*)(dl + (grow << 8) + j0) = lo8;
  };

  // 16-block row-group barrier, agent scope (works across XCDs)
  auto rgbar = [&](unsigned int epoch) {
    __syncthreads();
    if (tid == 0) {
      unsigned int* c = cnt + (rg << 6);   // 256B-padded counter per rg
      __hip_atomic_fetch_add(c, 1u, __ATOMIC_RELEASE, __HIP_MEMORY_SCOPE_AGENT);
      const unsigned int tgt = epoch << 4;
      while (__hip_atomic_load(c, __ATOMIC_ACQUIRE, __HIP_MEMORY_SCOPE_AGENT) < tgt)
        __builtin_amdgcn_s_sleep(2);
    }
    __syncthreads();
  };

  stem_slice(0, st_hi0, st_lo0);
  rgbar(1);   // weights in LDS + stem(0) + h0(memset) visible

  unsigned int epoch = 2;
  #pragma unroll 1
  for (int step = 0; step < T_OBS_C + T_UNOBS_C - 1; ++step) {
    const bool obs = (step < T_OBS_C);
    const unsigned short* hih = (step & 1) ? h_hi1 : h_hi0;
    const unsigned short* hil = (step & 1) ? h_lo1 : h_lo0;
    unsigned short* hoh = (step & 1) ? h_hi0 : h_hi1;
    unsigned short* hol = (step & 1) ? h_lo0 : h_lo1;
    const unsigned short* sxh = obs ? ((step & 1) ? st_hi1 : st_hi0) : hih;
    const unsigned short* sxl = obs ? ((step & 1) ? st_lo1 : st_lo0) : hil;
    const int matx = obs ? 0 : 1;   // wc : wi
    const int zi = (step == T_OBS_C - 1) ? 0
                   : (step >= T_OBS_C ? step - (T_OBS_C - 1) : -1);

    v4f aX[2][3], aH[2][3];
    #pragma unroll
    for (int mt = 0; mt < 2; ++mt)
      #pragma unroll
      for (int g = 0; g < 3; ++g) {
        aX[mt][g] = (v4f){0.f, 0.f, 0.f, 0.f};
        aH[mt][g] = (v4f){0.f, 0.f, 0.f, 0.f};
      }

    #pragma unroll
    for (int kc = 0; kc < 8; ++kc) {
      const size_t ko = (size_t)(kc * 32 + quad * 8);
      v8s ax0h = *(const v8s*)(sxh + rowA0 + ko);
      v8s ax0l = *(const v8s*)(sxl + rowA0 + ko);
      v8s ax1h = *(const v8s*)(sxh + rowA1 + ko);
      v8s ax1l = *(const v8s*)(sxl + rowA1 + ko);
      v8s ah0h, ah0l, ah1h, ah1l;
      if (obs) {
        ah0h = *(const v8s*)(hih + rowA0 + ko);
        ah0l = *(const v8s*)(hil + rowA0 + ko);
        ah1h = *(const v8s*)(hih + rowA1 + ko);
        ah1l = *(const v8s*)(hil + rowA1 + ko);
      } else {  // AR: x input == h
        ah0h = ax0h; ah0l = ax0l; ah1h = ax1h; ah1l = ax1l;
      }
      const int lrow = (l16 << 8) + ((((kc * 4 + quad) ^ l16)) << 3);
      #pragma unroll
      for (int g = 0; g < 3; ++g) {
        const v8s bxh = *(const v8s*)(wlds + (((matx * 3 + g) * 2 + 0) << 12) + lrow);
        const v8s bxl = *(const v8s*)(wlds + (((matx * 3 + g) * 2 + 1) << 12) + lrow);
        const v8s bhh = *(const v8s*)(wlds + (((6 + g) * 2 + 0) << 12) + lrow);
        const v8s bhl = *(const v8s*)(wlds + (((6 + g) * 2 + 1) << 12) + lrow);
        aX[0][g] = __builtin_amdgcn_mfma_f32_16x16x32_bf16(ax0h, bxh, aX[0][g], 0, 0, 0);
        aX[0][g] = __builtin_amdgcn_mfma_f32_16x16x32_bf16(ax0l, bxh, aX[0][g], 0, 0, 0);
        aX[0][g] = __builtin_amdgcn_mfma_f32_16x16x32_bf16(ax0h, bxl, aX[0][g], 0, 0, 0);
        aX[1][g] = __builtin_amdgcn_mfma_f32_16x16x32_bf16(ax1h, bxh, aX[1][g], 0, 0, 0);
        aX[1][g] = __builtin_amdgcn_mfma_f32_16x16x32_bf16(ax1l, bxh, aX[1][g], 0, 0, 0);
        aX[1][g] = __builtin_amdgcn_mfma_f32_16x16x32_bf16(ax1h, bxl, aX[1][g], 0, 0, 0);
        aH[0][g] = __builtin_amdgcn_mfma_f32_16x16x32_bf16(ah0h, bhh, aH[0][g], 0, 0, 0);
        aH[0][g] = __builtin_amdgcn_mfma_f32_16x16x32_bf16(ah0l, bhh, aH[0][g], 0, 0, 0);
        aH[0][g] = __builtin_amdgcn_mfma_f32_16x16x32_bf16(ah0h, bhl, aH[0][g], 0, 0, 0);
        aH[1][g] = __builtin_amdgcn_mfma_f32_16x16x32_bf16(ah1h, bhh, aH[1][g], 0, 0, 0);
        aH[1][g] = __builtin_amdgcn_mfma_f32_16x16x32_bf16(ah1l, bhh, aH[1][g], 0, 0, 0);
        aH[1][g] = __builtin_amdgcn_mfma_f32_16x16x32_bf16(ah1h, bhl, aH[1][g], 0, 0, 0);
      }
    }

    // ---- gate epilogue: thread owns col jc, rows (2w+mt)*16 + quad*4 + r ----
    #pragma unroll
    for (int mt = 0; mt < 2; ++mt) {
      #pragma unroll
      for (int r = 0; r < 4; ++r) {
        const int grow = m0 + (wave * 2 + mt) * 16 + quad * 4 + r;
        const size_t hoff = ((size_t)grow << 8) + jc;
        const float xbr = obs ? xb_o[0] : xb_a[0];
        const float xbz = obs ? xb_o[1] : xb_a[1];
        const float xbn = obs ? xb_o[2] : xb_a[2];
        float gr = aX[mt][0][r] + xbr + aH[mt][0][r] + hb_[0];
        float gz = aX[mt][1][r] + xbz + aH[mt][1][r] + hb_[1];
        float nx = aX[mt][2][r] + xbn;
        float nh = aH[mt][2][r] + hb_[2];
        float rr = 1.f / (1.f + expf(-gr));
        float uu = 1.f / (1.f + expf(-gz));
        float nn = tanhf(nx + rr * nh);
        float hold = bf2f(hih[hoff]) + bf2f(hil[hoff]);
        float hnew = (1.f - uu) * nn + uu * hold;
        unsigned short hi = f2bf(hnew);
        hoh[hoff] = hi;
        hol[hoff] = f2bf(hnew - bf2f(hi));
        if (zi >= 0) {
          out_z[((size_t)zi << 20) + hoff] = hnew;
          #pragma unroll
          for (int d = 0; d < 4; ++d) {
            float pd = hnew * hwv[d];
            pd += __shfl_xor(pd, 1);
            pd += __shfl_xor(pd, 2);
            pd += __shfl_xor(pd, 4);
            pd += __shfl_xor(pd, 8);
            if (l16 == 0) {
              if (cg == 0) pd += head_b[d];
              atomicAdd(out_x + ((((size_t)zi << 12) + grow) << 2) + d, pd);
            }
          }
        }
      }
    }

    if (obs && step + 1 < T_OBS_C)
      stem_slice(step + 1, ((step + 1) & 1) ? st_hi1 : st_hi0,
                           ((step + 1) & 1) ? st_lo1 : st_lo0);

    if (step < T_OBS_C + T_UNOBS_C - 2) rgbar(epoch++);
  }
}

// ---------------------------------------------------------------------------
extern "C" void kernel_launch(void* const* d_in, const int* in_sizes, int n_in,
                              void* d_out, int out_size, void* d_ws, size_t ws_size,
                              hipStream_t stream) {
  const float* x_obs = (const float*)d_in[0];
  const float* t_obs = (const float*)d_in[1];
  // d_in[2] = t_unobs: only its length (32) matters
  const float* w1 = (const float*)d_in[3];
  const float* b1 = (const float*)d_in[4];
  const float* w2 = (const float*)d_in[5];
  const float* b2 = (const float*)d_in[6];
  const float* wi = (const float*)d_in[7];
  const float* wh = (const float*)d_in[8];
  const float* bi = (const float*)d_in[9];
  const float* bh = (const float*)d_in[10];
  const float* hw = (const float*)d_in[11];
  const float* hb = (const float*)d_in[12];

  float* out_x = (float*)d_out;                                  // [32,4096,4]
  float* out_z = out_x + (size_t)T_UNOBS_C * BATCH_C * 4;        // [32,4096,256]

  // workspace: weights 2.36MB + h ping-pong 8MB + stem ping-pong 8MB (~19.2MB)
  unsigned short* p = (unsigned short*)d_ws;
  unsigned short* wi_hi = p; p += 768 * 256;
  unsigned short* wi_lo = p; p += 768 * 256;
  unsigned short* wh_hi = p; p += 768 * 256;
  unsigned short* wh_lo = p; p += 768 * 256;
  unsigned short* wc_hi = p; p += 768 * 256;
  unsigned short* wc_lo = p; p += 768 * 256;
  unsigned short* h_hi0 = p; p += (size_t)1 << 20;
  unsigned short* h_lo0 = p; p += (size_t)1 << 20;
  unsigned short* h_hi1 = p; p += (size_t)1 << 20;
  unsigned short* h_lo1 = p; p += (size_t)1 << 20;
  unsigned short* st_hi0 = p; p += (size_t)1 << 20;
  unsigned short* st_lo0 = p; p += (size_t)1 << 20;
  unsigned short* st_hi1 = p; p += (size_t)1 << 20;
  unsigned short* st_lo1 = p; p += (size_t)1 << 20;
  float* bc_obs = (float*)p; p += 768 * 2;
  unsigned int* cnt = (unsigned int*)p;            // 16 rgs x 64 u32 (padded)

  // h0 = 0 (h_hi0 + h_lo0 contiguous), counters = 0, out_x = 0 (atomic target)
  hipMemsetAsync(h_hi0, 0, (size_t)4 << 20, stream);
  hipMemsetAsync(cnt, 0, 16 * 64 * sizeof(unsigned int), stream);
  hipMemsetAsync(out_x, 0, (size_t)T_UNOBS_C * BATCH_C * 4 * sizeof(float), stream);

  prep_kernel<<<768, 256, 0, stream>>>(wi, w2, b2, bi,
                                       wi_hi, wi_lo, wh, wh_hi, wh_lo,
                                       wc_hi, wc_lo, bc_obs);

  void* args[] = {
    (void*)&x_obs, (void*)&t_obs, (void*)&w1, (void*)&b1,
    (void*)&wc_hi, (void*)&wc_lo, (void*)&wi_hi, (void*)&wi_lo,
    (void*)&wh_hi, (void*)&wh_lo,
    (void*)&bc_obs, (void*)&bi, (void*)&bh, (void*)&hw, (void*)&hb,
    (void*)&h_hi0, (void*)&h_lo0, (void*)&h_hi1, (void*)&h_lo1,
    (void*)&st_hi0, (void*)&st_lo0, (void*)&st_hi1, (void*)&st_lo1,
    (void*)&cnt, (void*)&out_x, (void*)&out_z
  };
  hipLaunchCooperativeKernel(reinterpret_cast<void*>(rnn_xcd),
                             dim3(256), dim3(512), args, 0, stream);
}

// Round 7
// 2873.415 us; speedup vs baseline: 3.4336x; 1.1442x over previous
//
#include <hip/hip_runtime.h>
#include <cstdint>
#include <cstddef>

#define T_OBS_C 64
#define T_UNOBS_C 32
#define BATCH_C 4096
#define HID_C 256

typedef short v8s __attribute__((ext_vector_type(8)));
typedef float v4f __attribute__((ext_vector_type(4)));
typedef unsigned short u16x8 __attribute__((ext_vector_type(8)));

__device__ __forceinline__ float bf2f(unsigned short u) {
  union { unsigned int i; float f; } v; v.i = ((unsigned int)u) << 16; return v.f;
}
__device__ __forceinline__ unsigned short f2bf(float f) {
  union { float f; unsigned int i; } v; v.f = f;
  unsigned int r = (v.i + 0x7FFFu + ((v.i >> 16) & 1u)) >> 16;
  return (unsigned short)r;
}

// ---------------------------------------------------------------------------
// prep (unchanged, verified):
//   Wc = wi @ stem_w2  -> hi/lo bf16 ; wi, wh -> hi/lo bf16
//   bc_obs[n] = sum_j wi[n][j]*b2[j] + bi[n]
// ---------------------------------------------------------------------------
__global__ void prep_kernel(const float* __restrict__ wi,
                            const float* __restrict__ w2,
                            const float* __restrict__ b2,
                            const float* __restrict__ bi,
                            unsigned short* __restrict__ wi_hi,
                            unsigned short* __restrict__ wi_lo,
                            const float* __restrict__ wh,
                            unsigned short* __restrict__ wh_hi,
                            unsigned short* __restrict__ wh_lo,
                            unsigned short* __restrict__ wc_hi,
                            unsigned short* __restrict__ wc_lo,
                            float* __restrict__ bc_obs) {
  const int n = blockIdx.x;     // 0..767
  const int k = threadIdx.x;    // 0..255
  const int idx = n * 256 + k;

  float wv = wi[idx];
  unsigned short h1 = f2bf(wv);
  wi_hi[idx] = h1; wi_lo[idx] = f2bf(wv - bf2f(h1));

  float hv = wh[idx];
  unsigned short h2 = f2bf(hv);
  wh_hi[idx] = h2; wh_lo[idx] = f2bf(hv - bf2f(h2));

  float acc = 0.f;
  for (int j = 0; j < 256; ++j)
    acc += wi[n * 256 + j] * w2[j * 256 + k];
  unsigned short h3 = f2bf(acc);
  wc_hi[idx] = h3; wc_lo[idx] = f2bf(acc - bf2f(h3));

  if (k == 0) {
    float b = 0.f;
    for (int j = 0; j < 256; ++j) b += wi[n * 256 + j] * b2[j];
    bc_obs[n] = b + bi[n];
  }
}

// ---------------------------------------------------------------------------
// Weight-stationary persistent RNN, v2.
// 256 blocks = 16 row-groups (256 rows) x 16 col-groups (16 h-cols).
// Weight slices (wc,wi,wh hi/lo = 144KB) + W1/b1 (6KB) live in LDS forever.
// NEW vs round 6:
//  - stem exchange eliminated: each block computes its stem A-fragments
//    in registers from x (K=5) + LDS W1 -> only h is exchanged per step.
//  - obs x-path GEMM (aXp) computed PRE-barrier for the next step (depends
//    only on x[t+1] + LDS Wc) -> post-barrier obs work = h-path only.
// Barrier/mapping/epilogue identical to the round-6 passing kernel.
// ---------------------------------------------------------------------------
__global__ __launch_bounds__(512, 2)
void rnn_ws2(const float* __restrict__ x_obs,
             const float* __restrict__ t_obs,
             const float* __restrict__ w1,
             const float* __restrict__ b1,
             const unsigned short* __restrict__ wc_hi, const unsigned short* __restrict__ wc_lo,
             const unsigned short* __restrict__ wi_hi, const unsigned short* __restrict__ wi_lo,
             const unsigned short* __restrict__ wh_hi, const unsigned short* __restrict__ wh_lo,
             const float* __restrict__ bc_obs,
             const float* __restrict__ bi,
             const float* __restrict__ bh,
             const float* __restrict__ head_w,
             const float* __restrict__ head_b,
             unsigned short* h_hi0, unsigned short* h_lo0,
             unsigned short* h_hi1, unsigned short* h_lo1,
             unsigned int* cnt,
             float* out_x,
             float* out_z) {
  // [(mat*3+g)*2+hl][16 rows][32 c16-chunks swizzled] = 18*4096 ushorts = 144KB
  __shared__ unsigned short wlds[73728];
  __shared__ float w1t[1280];   // [5][256] transposed stem weights
  __shared__ float b1s[256];

  const int tid = threadIdx.x;
  const int bid = blockIdx.x;
  const int jj  = bid & 15;
  const int cg  = bid >> 4;
  const int rg  = ((jj & 7) << 1) | (jj >> 3);   // same-rg blocks share XCD (perf)
  const int m0  = rg << 8;                       // 256 rows per row-group
  const int c0  = cg << 4;                       // 16 h-cols per col-group

  // ---- one-time: weight slices + stem weights into LDS ----
  {
    const unsigned short* srcs[6] = {wc_hi, wc_lo, wi_hi, wi_lo, wh_hi, wh_lo};
    for (int id = tid; id < 9216; id += 512) {
      const int sub = id >> 9;                 // 0..17 == (mat*3+g)*2+hl
      const int mat = sub / 6;
      const int g   = (sub >> 1) % 3;
      const int hl  = sub & 1;
      const int within = id & 511;
      const int row = within >> 5;             // 0..15
      const int c16 = within & 31;
      const unsigned short* s = srcs[mat * 2 + hl] +
          (((size_t)(g * 256 + c0 + row)) << 8) + (c16 << 3);
      u16x8 v = *(const u16x8*)s;
      *(u16x8*)(wlds + (sub << 12) + (row << 8) + ((c16 ^ row) << 3)) = v;
    }
    for (int i = tid; i < 1280; i += 512) {
      const int k = i / 5, j = i - k * 5;
      w1t[j * 256 + k] = w1[i];
    }
    if (tid < 256) b1s[tid] = b1[tid];
  }

  const int wave = tid >> 6;      // 0..7, owns m-tiles {2w, 2w+1}
  const int lane = tid & 63;
  const int quad = lane >> 4;
  const int l16  = lane & 15;
  const int jc   = c0 + l16;      // this thread's h-col

  float xb_o[3], xb_a[3], hb_[3], hwv[4];
  #pragma unroll
  for (int g = 0; g < 3; ++g) {
    xb_o[g] = bc_obs[g * 256 + jc];
    xb_a[g] = bi[g * 256 + jc];
    hb_[g]  = bh[g * 256 + jc];
  }
  #pragma unroll
  for (int d = 0; d < 4; ++d) hwv[d] = head_w[d * 256 + jc];

  const int rowL0 = (wave * 2 + 0) * 16 + l16;   // local rows 0..255
  const int rowL1 = (wave * 2 + 1) * 16 + l16;
  const size_t rowA0 = (size_t)(m0 + rowL0) << 8;
  const size_t rowA1 = (size_t)(m0 + rowL1) << 8;

  // 16-block row-group barrier, agent scope (verbatim round 6)
  auto rgbar = [&](unsigned int epoch) {
    __syncthreads();
    if (tid == 0) {
      unsigned int* c = cnt + (rg << 6);
      __hip_atomic_fetch_add(c, 1u, __ATOMIC_RELEASE, __HIP_MEMORY_SCOPE_AGENT);
      const unsigned int tgt = epoch << 4;
      while (__hip_atomic_load(c, __ATOMIC_ACQUIRE, __HIP_MEMORY_SCOPE_AGENT) < tgt)
        __builtin_amdgcn_s_sleep(2);
    }
    __syncthreads();
  };

  __syncthreads();   // LDS weights ready

  // x-state for the next obs step (registers)
  float4 xv0, xv1; float td0 = 0.f, td1 = 0.f;
  auto load_x = [&](int tt) {
    const size_t xo0 = (size_t)tt * BATCH_C + m0 + rowL0;
    const size_t xo1 = (size_t)tt * BATCH_C + m0 + rowL1;
    xv0 = *(const float4*)(x_obs + xo0 * 4);
    xv1 = *(const float4*)(x_obs + xo1 * 4);
    if (tt > 0) {
      td0 = t_obs[xo0] - t_obs[xo0 - BATCH_C];
      td1 = t_obs[xo1] - t_obs[xo1 - BATCH_C];
    } else { td0 = 0.f; td1 = 0.f; }
  };

  // pre-barrier obs x-path: stem fragments on the fly + MFMA vs LDS Wc slice
  v4f aXp[2][3];
  auto xpath_pre = [&]() {
    #pragma unroll
    for (int mt = 0; mt < 2; ++mt)
      #pragma unroll
      for (int g = 0; g < 3; ++g)
        aXp[mt][g] = (v4f){0.f, 0.f, 0.f, 0.f};
    #pragma unroll
    for (int kc = 0; kc < 8; ++kc) {
      v8s s0h, s0l, s1h, s1l;
      #pragma unroll
      for (int j = 0; j < 8; ++j) {
        const int k = kc * 32 + quad * 8 + j;
        const float wA = w1t[k], wB = w1t[256 + k], wC = w1t[512 + k],
                    wD = w1t[768 + k], wE = w1t[1024 + k];
        const float bb = b1s[k];
        float p0 = xv0.x * wA + xv0.y * wB + xv0.z * wC + xv0.w * wD + td0 * wE + bb;
        float a0 = (p0 > 0.f) ? p0 : 0.01f * p0;    // leaky_relu 0.01
        unsigned short h0 = f2bf(a0);
        s0h[j] = h0; s0l[j] = f2bf(a0 - bf2f(h0));
        float p1 = xv1.x * wA + xv1.y * wB + xv1.z * wC + xv1.w * wD + td1 * wE + bb;
        float a1 = (p1 > 0.f) ? p1 : 0.01f * p1;
        unsigned short h1 = f2bf(a1);
        s1h[j] = h1; s1l[j] = f2bf(a1 - bf2f(h1));
      }
      const int lrow = (l16 << 8) + ((((kc * 4 + quad) ^ l16)) << 3);
      #pragma unroll
      for (int g = 0; g < 3; ++g) {
        const v8s bxh = *(const v8s*)(wlds + ((g * 2 + 0) << 12) + lrow);  // wc hi
        const v8s bxl = *(const v8s*)(wlds + ((g * 2 + 1) << 12) + lrow);  // wc lo
        aXp[0][g] = __builtin_amdgcn_mfma_f32_16x16x32_bf16(s0h, bxh, aXp[0][g], 0, 0, 0);
        aXp[0][g] = __builtin_amdgcn_mfma_f32_16x16x32_bf16(s0l, bxh, aXp[0][g], 0, 0, 0);
        aXp[0][g] = __builtin_amdgcn_mfma_f32_16x16x32_bf16(s0h, bxl, aXp[0][g], 0, 0, 0);
        aXp[1][g] = __builtin_amdgcn_mfma_f32_16x16x32_bf16(s1h, bxh, aXp[1][g], 0, 0, 0);
        aXp[1][g] = __builtin_amdgcn_mfma_f32_16x16x32_bf16(s1l, bxh, aXp[1][g], 0, 0, 0);
        aXp[1][g] = __builtin_amdgcn_mfma_f32_16x16x32_bf16(s1h, bxl, aXp[1][g], 0, 0, 0);
      }
    }
  };

  load_x(0);
  xpath_pre();        // step 0's x-path, before the first barrier
  rgbar(1);           // weights staged + h0(memset) visible

  unsigned int epoch = 2;
  #pragma unroll 1
  for (int step = 0; step < T_OBS_C + T_UNOBS_C - 1; ++step) {
    const bool obs = (step < T_OBS_C);
    const unsigned short* hih = (step & 1) ? h_hi1 : h_hi0;
    const unsigned short* hil = (step & 1) ? h_lo1 : h_lo0;
    unsigned short* hoh = (step & 1) ? h_hi0 : h_hi1;
    unsigned short* hol = (step & 1) ? h_lo0 : h_lo1;
    const int zi = (step == T_OBS_C - 1) ? 0
                   : (step >= T_OBS_C ? step - (T_OBS_C - 1) : -1);

    v4f aX[2][3], aH[2][3];
    #pragma unroll
    for (int mt = 0; mt < 2; ++mt)
      #pragma unroll
      for (int g = 0; g < 3; ++g) {
        aX[mt][g] = obs ? aXp[mt][g] : (v4f){0.f, 0.f, 0.f, 0.f};
        aH[mt][g] = (v4f){0.f, 0.f, 0.f, 0.f};
      }

    const bool nextobs = (step + 1 < T_OBS_C);
    if (nextobs) load_x(step + 1);   // issue early; consumed post-epilogue

    if (obs) {
      // h-path only (x-path was pre-computed)
      #pragma unroll
      for (int kc = 0; kc < 8; ++kc) {
        const size_t ko = (size_t)(kc * 32 + quad * 8);
        const v8s ah0h = *(const v8s*)(hih + rowA0 + ko);
        const v8s ah0l = *(const v8s*)(hil + rowA0 + ko);
        const v8s ah1h = *(const v8s*)(hih + rowA1 + ko);
        const v8s ah1l = *(const v8s*)(hil + rowA1 + ko);
        const int lrow = (l16 << 8) + ((((kc * 4 + quad) ^ l16)) << 3);
        #pragma unroll
        for (int g = 0; g < 3; ++g) {
          const v8s bhh = *(const v8s*)(wlds + (((6 + g) * 2 + 0) << 12) + lrow);
          const v8s bhl = *(const v8s*)(wlds + (((6 + g) * 2 + 1) << 12) + lrow);
          aH[0][g] = __builtin_amdgcn_mfma_f32_16x16x32_bf16(ah0h, bhh, aH[0][g], 0, 0, 0);
          aH[0][g] = __builtin_amdgcn_mfma_f32_16x16x32_bf16(ah0l, bhh, aH[0][g], 0, 0, 0);
          aH[0][g] = __builtin_amdgcn_mfma_f32_16x16x32_bf16(ah0h, bhl, aH[0][g], 0, 0, 0);
          aH[1][g] = __builtin_amdgcn_mfma_f32_16x16x32_bf16(ah1h, bhh, aH[1][g], 0, 0, 0);
          aH[1][g] = __builtin_amdgcn_mfma_f32_16x16x32_bf16(ah1l, bhh, aH[1][g], 0, 0, 0);
          aH[1][g] = __builtin_amdgcn_mfma_f32_16x16x32_bf16(ah1h, bhl, aH[1][g], 0, 0, 0);
        }
      }
    } else {
      // AR: x == h, both paths post-barrier, A loads shared
      #pragma unroll
      for (int kc = 0; kc < 8; ++kc) {
        const size_t ko = (size_t)(kc * 32 + quad * 8);
        const v8s ah0h = *(const v8s*)(hih + rowA0 + ko);
        const v8s ah0l = *(const v8s*)(hil + rowA0 + ko);
        const v8s ah1h = *(const v8s*)(hih + rowA1 + ko);
        const v8s ah1l = *(const v8s*)(hil + rowA1 + ko);
        const int lrow = (l16 << 8) + ((((kc * 4 + quad) ^ l16)) << 3);
        #pragma unroll
        for (int g = 0; g < 3; ++g) {
          const v8s bxh = *(const v8s*)(wlds + (((3 + g) * 2 + 0) << 12) + lrow);  // wi
          const v8s bxl = *(const v8s*)(wlds + (((3 + g) * 2 + 1) << 12) + lrow);
          const v8s bhh = *(const v8s*)(wlds + (((6 + g) * 2 + 0) << 12) + lrow);  // wh
          const v8s bhl = *(const v8s*)(wlds + (((6 + g) * 2 + 1) << 12) + lrow);
          aX[0][g] = __builtin_amdgcn_mfma_f32_16x16x32_bf16(ah0h, bxh, aX[0][g], 0, 0, 0);
          aX[0][g] = __builtin_amdgcn_mfma_f32_16x16x32_bf16(ah0l, bxh, aX[0][g], 0, 0, 0);
          aX[0][g] = __builtin_amdgcn_mfma_f32_16x16x32_bf16(ah0h, bxl, aX[0][g], 0, 0, 0);
          aX[1][g] = __builtin_amdgcn_mfma_f32_16x16x32_bf16(ah1h, bxh, aX[1][g], 0, 0, 0);
          aX[1][g] = __builtin_amdgcn_mfma_f32_16x16x32_bf16(ah1l, bxh, aX[1][g], 0, 0, 0);
          aX[1][g] = __builtin_amdgcn_mfma_f32_16x16x32_bf16(ah1h, bxl, aX[1][g], 0, 0, 0);
          aH[0][g] = __builtin_amdgcn_mfma_f32_16x16x32_bf16(ah0h, bhh, aH[0][g], 0, 0, 0);
          aH[0][g] = __builtin_amdgcn_mfma_f32_16x16x32_bf16(ah0l, bhh, aH[0][g], 0, 0, 0);
          aH[0][g] = __builtin_amdgcn_mfma_f32_16x16x32_bf16(ah0h, bhl, aH[0][g], 0, 0, 0);
          aH[1][g] = __builtin_amdgcn_mfma_f32_16x16x32_bf16(ah1h, bhh, aH[1][g], 0, 0, 0);
          aH[1][g] = __builtin_amdgcn_mfma_f32_16x16x32_bf16(ah1l, bhh, aH[1][g], 0, 0, 0);
          aH[1][g] = __builtin_amdgcn_mfma_f32_16x16x32_bf16(ah1h, bhl, aH[1][g], 0, 0, 0);
        }
      }
    }

    // ---- gate epilogue (verbatim round 6) ----
    #pragma unroll
    for (int mt = 0; mt < 2; ++mt) {
      #pragma unroll
      for (int r = 0; r < 4; ++r) {
        const int grow = m0 + (wave * 2 + mt) * 16 + quad * 4 + r;
        const size_t hoff = ((size_t)grow << 8) + jc;
        const float xbr = obs ? xb_o[0] : xb_a[0];
        const float xbz = obs ? xb_o[1] : xb_a[1];
        const float xbn = obs ? xb_o[2] : xb_a[2];
        float gr = aX[mt][0][r] + xbr + aH[mt][0][r] + hb_[0];
        float gz = aX[mt][1][r] + xbz + aH[mt][1][r] + hb_[1];
        float nx = aX[mt][2][r] + xbn;
        float nh = aH[mt][2][r] + hb_[2];
        float rr = 1.f / (1.f + expf(-gr));
        float uu = 1.f / (1.f + expf(-gz));
        float nn = tanhf(nx + rr * nh);
        float hold = bf2f(hih[hoff]) + bf2f(hil[hoff]);
        float hnew = (1.f - uu) * nn + uu * hold;
        unsigned short hi = f2bf(hnew);
        hoh[hoff] = hi;
        hol[hoff] = f2bf(hnew - bf2f(hi));
        if (zi >= 0) {
          out_z[((size_t)zi << 20) + hoff] = hnew;
          #pragma unroll
          for (int d = 0; d < 4; ++d) {
            float pd = hnew * hwv[d];
            pd += __shfl_xor(pd, 1);
            pd += __shfl_xor(pd, 2);
            pd += __shfl_xor(pd, 4);
            pd += __shfl_xor(pd, 8);
            if (l16 == 0) {
              if (cg == 0) pd += head_b[d];
              atomicAdd(out_x + ((((size_t)zi << 12) + grow) << 2) + d, pd);
            }
          }
        }
      }
    }

    if (nextobs) xpath_pre();    // next step's x-path, in the straggler shadow

    if (step < T_OBS_C + T_UNOBS_C - 2) rgbar(epoch++);
  }
}

// ---------------------------------------------------------------------------
extern "C" void kernel_launch(void* const* d_in, const int* in_sizes, int n_in,
                              void* d_out, int out_size, void* d_ws, size_t ws_size,
                              hipStream_t stream) {
  const float* x_obs = (const float*)d_in[0];
  const float* t_obs = (const float*)d_in[1];
  // d_in[2] = t_unobs: only its length (32) matters
  const float* w1 = (const float*)d_in[3];
  const float* b1 = (const float*)d_in[4];
  const float* w2 = (const float*)d_in[5];
  const float* b2 = (const float*)d_in[6];
  const float* wi = (const float*)d_in[7];
  const float* wh = (const float*)d_in[8];
  const float* bi = (const float*)d_in[9];
  const float* bh = (const float*)d_in[10];
  const float* hw = (const float*)d_in[11];
  const float* hb = (const float*)d_in[12];

  float* out_x = (float*)d_out;                                  // [32,4096,4]
  float* out_z = out_x + (size_t)T_UNOBS_C * BATCH_C * 4;        // [32,4096,256]

  // workspace: weights 2.36MB + h ping-pong 8MB (~11 MB)
  unsigned short* p = (unsigned short*)d_ws;
  unsigned short* wi_hi = p; p += 768 * 256;
  unsigned short* wi_lo = p; p += 768 * 256;
  unsigned short* wh_hi = p; p += 768 * 256;
  unsigned short* wh_lo = p; p += 768 * 256;
  unsigned short* wc_hi = p; p += 768 * 256;
  unsigned short* wc_lo = p; p += 768 * 256;
  unsigned short* h_hi0 = p; p += (size_t)1 << 20;
  unsigned short* h_lo0 = p; p += (size_t)1 << 20;
  unsigned short* h_hi1 = p; p += (size_t)1 << 20;
  unsigned short* h_lo1 = p; p += (size_t)1 << 20;
  float* bc_obs = (float*)p; p += 768 * 2;
  unsigned int* cnt = (unsigned int*)p;            // 16 rgs x 64 u32 (padded)

  // h0 = 0 (h_hi0 + h_lo0 contiguous), counters = 0, out_x = 0 (atomic target)
  hipMemsetAsync(h_hi0, 0, (size_t)4 << 20, stream);
  hipMemsetAsync(cnt, 0, 16 * 64 * sizeof(unsigned int), stream);
  hipMemsetAsync(out_x, 0, (size_t)T_UNOBS_C * BATCH_C * 4 * sizeof(float), stream);

  prep_kernel<<<768, 256, 0, stream>>>(wi, w2, b2, bi,
                                       wi_hi, wi_lo, wh, wh_hi, wh_lo,
                                       wc_hi, wc_lo, bc_obs);

  void* args[] = {
    (void*)&x_obs, (void*)&t_obs, (void*)&w1, (void*)&b1,
    (void*)&wc_hi, (void*)&wc_lo, (void*)&wi_hi, (void*)&wi_lo,
    (void*)&wh_hi, (void*)&wh_lo,
    (void*)&bc_obs, (void*)&bi, (void*)&bh, (void*)&hw, (void*)&hb,
    (void*)&h_hi0, (void*)&h_lo0, (void*)&h_hi1, (void*)&h_lo1,
    (void*)&cnt, (void*)&out_x, (void*)&out_z
  };
  hipLaunchCooperativeKernel(reinterpret_cast<void*>(rnn_ws2),
                             dim3(256), dim3(512), args, 0, stream);
}